// Round 1
// baseline (294.231 us; speedup 1.0000x reference)
//
#include <hip/hip_runtime.h>

// LoRA forward: out[8192][4096] = (x[8192][4096] @ A^T[4096][16]) @ B^T[16][4096] * 2.0
// All fp32. Memory-bound: 128 MiB x read + 128 MiB out write -> ~43 us roofline.
//
// ws layout (needs 8.25 MB):
//   At [4096][16] f32 @ 0        (256 KB)  -- A transposed so stage1 can s_load rows
//   hp [8192][16][16] f32 @ 256K (8 MB)    -- 16 K-split partials of h, [row][rank][ksplit]

#define IN_F  4096
#define OUT_F 4096
#define RANK  16

// ---------------- stage 0: transpose A[16][4096] -> At[4096][16] ----------------
__global__ __launch_bounds__(256) void k_transpose(const float* __restrict__ A,
                                                   float* __restrict__ At) {
    int idx = blockIdx.x * 256 + threadIdx.x;   // 0..65535
    int r = idx >> 12;                          // 0..15  (row of A)
    int k = idx & 4095;                         // col of A
    At[k * RANK + r] = A[idx];
}

// ---------------- stage 1: hp[row][rank][ks] = partial x @ A^T ----------------
// grid = 512 = 128 row-groups(64 rows) x 4 k-blocks(1024 k). Each of the 4 waves
// takes a 256-k sub-slice -> global ksplit id = (b&3)*4 + w  in [0,16).
// lane = row within the group; A-operand is wave-uniform -> SGPR fmac operand.
__global__ __launch_bounds__(256) void k_stage1(const float* __restrict__ x,
                                                const float* __restrict__ At,
                                                float* __restrict__ hp) {
    __shared__ float xs[4 * 64 * 36];           // per-wave [64 rows][32k + 4 pad]
    const int tid  = threadIdx.x;
    const int w    = __builtin_amdgcn_readfirstlane(tid >> 6);  // force wave-uniform
    const int lane = tid & 63;
    const int b    = blockIdx.x;
    const int row0 = (b >> 2) * 64;
    const int kw   = (b & 3) * 1024 + w * 256;  // this wave's 256-k slice

    float p[RANK];
#pragma unroll
    for (int i = 0; i < RANK; ++i) p[i] = 0.0f;

    float* xw = xs + w * (64 * 36);
    const int rs = lane >> 3;        // 0..7  staging row sub-index
    const int kl = (lane & 7) * 4;   // 0..28 staging k offset (float4)

    for (int c = 0; c < 8; ++c) {
        const int kc = kw + c * 32;
        // stage x[row0..row0+63][kc..kc+31] -> xw. 128B segments, coalesced.
        // No barrier needed: this wave is the only consumer of xw.
#pragma unroll
        for (int i = 0; i < 8; ++i) {
            const int r = i * 8 + rs;
            const float4 v = *(const float4*)(x + (size_t)(row0 + r) * IN_F + (kc + kl));
            *(float4*)(xw + r * 36 + kl) = v;
        }
        // compute: lane owns row (row0+lane). Stride 36 words -> banks (4*lane+k)%32, clean.
        for (int k = 0; k < 32; k += 4) {
            const float4 xv = *(const float4*)(xw + lane * 36 + k);
            const float* a  = At + (size_t)(kc + k) * RANK;   // wave-uniform -> s_load
#pragma unroll
            for (int r = 0; r < RANK; ++r) p[r] += xv.x * a[r];
#pragma unroll
            for (int r = 0; r < RANK; ++r) p[r] += xv.y * a[RANK + r];
#pragma unroll
            for (int r = 0; r < RANK; ++r) p[r] += xv.z * a[2 * RANK + r];
#pragma unroll
            for (int r = 0; r < RANK; ++r) p[r] += xv.w * a[3 * RANK + r];
        }
    }
    const int ks = (b & 3) * 4 + w;             // 0..15
    const size_t row = (size_t)row0 + lane;
#pragma unroll
    for (int r = 0; r < RANK; ++r)
        hp[(row * RANK + r) * 16 + ks] = p[r];
}

// ---------------- stage 2: out = (sum_ks hp) @ B^T * 2 ----------------
// grid = 512 = 128 row-groups(64 rows) x 4 o-blocks(1024 cols).
// Thread owns 4 output cols: B[o..o+3][0:16] in 64 VGPRs, h broadcast from LDS.
__global__ __launch_bounds__(256) void k_stage2(const float* __restrict__ hp,
                                                const float* __restrict__ B,
                                                float* __restrict__ out) {
    __shared__ float hs[64 * RANK];             // 4 KB
    const int tid  = threadIdx.x;
    const int b    = blockIdx.x;
    const int row0 = (b >> 2) * 64;
    const int o    = (b & 3) * 1024 + tid * 4;

    // reduce the 16 K-split partials: each (row,rank) pair = 16 contiguous floats
#pragma unroll
    for (int i = 0; i < 4; ++i) {
        const int idx = i * 256 + tid;          // 0..1023 = 64 rows x 16 ranks
        const float4* h4 = (const float4*)(hp + ((size_t)row0 * RANK + idx) * 16);
        const float4 a = h4[0], c = h4[1], d = h4[2], e = h4[3];
        hs[idx] = 2.0f * (a.x + a.y + a.z + a.w + c.x + c.y + c.z + c.w +
                          d.x + d.y + d.z + d.w + e.x + e.y + e.z + e.w);
    }

    // B slice into regs: bf[j*16 + rho] = B[o+j][rho]
    float4 breg[16];
    const float4* B4 = (const float4*)B;
#pragma unroll
    for (int i = 0; i < 16; ++i) breg[i] = B4[(size_t)o * 4 + i];
    const float* bf = (const float*)breg;
    __syncthreads();

    for (int r = 0; r < 64; ++r) {
        const float4 h0 = *(const float4*)(hs + r * RANK);
        const float4 h1 = *(const float4*)(hs + r * RANK + 4);
        const float4 h2 = *(const float4*)(hs + r * RANK + 8);
        const float4 h3 = *(const float4*)(hs + r * RANK + 12);
        const float hv[16] = {h0.x, h0.y, h0.z, h0.w, h1.x, h1.y, h1.z, h1.w,
                              h2.x, h2.y, h2.z, h2.w, h3.x, h3.y, h3.z, h3.w};
        float4 acc = {0.f, 0.f, 0.f, 0.f};
#pragma unroll
        for (int rho = 0; rho < 16; ++rho) {
            acc.x += hv[rho] * bf[0 * 16 + rho];
            acc.y += hv[rho] * bf[1 * 16 + rho];
            acc.z += hv[rho] * bf[2 * 16 + rho];
            acc.w += hv[rho] * bf[3 * 16 + rho];
        }
        *(float4*)(out + (size_t)(row0 + r) * OUT_F + o) = acc;   // coalesced dwordx4
    }
}

extern "C" void kernel_launch(void* const* d_in, const int* in_sizes, int n_in,
                              void* d_out, int out_size, void* d_ws, size_t ws_size,
                              hipStream_t stream) {
    const float* x  = (const float*)d_in[0];   // [4,2048,4096]
    const float* A  = (const float*)d_in[1];   // [16,4096]
    const float* Bm = (const float*)d_in[2];   // [4096,16]
    float* out = (float*)d_out;                // [4,2048,4096] fp32
    float* At  = (float*)d_ws;                                   // 256 KB
    float* hp  = (float*)((char*)d_ws + (size_t)IN_F * RANK * 4); // 8 MB

    k_transpose<<<256, 256, 0, stream>>>(A, At);
    k_stage1<<<512, 256, 0, stream>>>(x, At, hp);
    k_stage2<<<512, 256, 0, stream>>>(hp, Bm, out);
}

// Round 2
// 291.236 us; speedup vs baseline: 1.0103x; 1.0103x over previous
//
#include <hip/hip_runtime.h>

// LoRA forward: out[8192][4096] = (x[8192][4096] @ A^T) @ B^T * 2.0, all fp32.
// Memory-bound: 128 MiB x read + 128 MiB out write -> ~43 us floor.
//
// ws layout (16.25 MB of the ~512 MiB workspace):
//   At [4096][16] f32 @ 0       (256 KB)  -- A transposed so stage1 A-operand is s_load
//   hp [32][8192][16] f32 @256K (16 MB)   -- 32 K-split partials of h, [ksplit][row][rank]

#define IN_F  4096
#define OUT_F 4096
#define RANK  16
#define KSPLIT 32           // k-splits in stage1; each wave owns 128 k
#define KSLICE 128

// ---------------- stage 0: transpose A[16][4096] -> At[4096][16] ----------------
__global__ __launch_bounds__(256) void k_transpose(const float* __restrict__ A,
                                                   float* __restrict__ At) {
    int idx = blockIdx.x * 256 + threadIdx.x;   // 0..65535
    int r = idx >> 12;                          // row of A (0..15)
    int k = idx & 4095;                         // col of A
    At[k * RANK + r] = A[idx];
}

// ---------------- stage 1: hp[ks][row][rank] = partial x @ A^T ----------------
// wave g = (row-group rg: 64 rows, k-split ks: 128 k). 4096 waves = 1024 blocks.
// lane owns row -> x loads are per-lane dwordx4 from own row (L1 assembles full
// lines across the 4 consecutive k-iterations). A-operand wave-uniform -> SGPR.
// No LDS, no barriers, ~16 waves/CU, 8 loads in flight per wave.
__global__ __launch_bounds__(256) void k_stage1(const float* __restrict__ x,
                                                const float* __restrict__ At,
                                                float* __restrict__ hp) {
    const int tid  = threadIdx.x;
    const int w    = __builtin_amdgcn_readfirstlane(tid >> 6);
    const int lane = tid & 63;
    const int g    = blockIdx.x * 4 + w;        // 0..4095
    const int rg   = g >> 5;                    // 0..127
    const int ks   = g & (KSPLIT - 1);          // 0..31
    const size_t row = (size_t)rg * 64 + lane;
    const int k0   = ks * KSLICE;

    const float* xr = x + row * IN_F + k0;

    float p[RANK];
#pragma unroll
    for (int r = 0; r < RANK; ++r) p[r] = 0.0f;

#pragma unroll 2
    for (int c = 0; c < 8; ++c) {               // 16 k per c-iter
        float4 v[4];
#pragma unroll
        for (int q = 0; q < 4; ++q)
            v[q] = *(const float4*)(xr + c * 16 + q * 4);
        const float* a = At + (size_t)(k0 + c * 16) * RANK;   // wave-uniform -> s_load
#pragma unroll
        for (int q = 0; q < 4; ++q) {
            const float* aq = a + q * 64;       // At rows for v[q].x..w
#pragma unroll
            for (int r = 0; r < RANK; ++r) p[r] += v[q].x * aq[r];
#pragma unroll
            for (int r = 0; r < RANK; ++r) p[r] += v[q].y * aq[RANK + r];
#pragma unroll
            for (int r = 0; r < RANK; ++r) p[r] += v[q].z * aq[2 * RANK + r];
#pragma unroll
            for (int r = 0; r < RANK; ++r) p[r] += v[q].w * aq[3 * RANK + r];
        }
    }

    // coalesced partial store: lanes (rows) stride 64 B
    float4* o = (float4*)(hp + ((size_t)ks * 8192 + row) * RANK);
    o[0] = make_float4(p[0],  p[1],  p[2],  p[3]);
    o[1] = make_float4(p[4],  p[5],  p[6],  p[7]);
    o[2] = make_float4(p[8],  p[9],  p[10], p[11]);
    o[3] = make_float4(p[12], p[13], p[14], p[15]);
}

// ---------------- stage 2: out = (sum_ks hp) @ B^T * 2 ----------------
// block = 32 rows x 1024 cols; grid = 256 row-groups x 4 col-blocks = 1024.
// Thread owns 4 cols (B slice in 64 VGPRs); h rows broadcast from LDS (2 KB).
__global__ __launch_bounds__(256) void k_stage2(const float* __restrict__ hp,
                                                const float* __restrict__ B,
                                                float* __restrict__ out) {
    __shared__ float hs[32 * RANK];             // 2 KB
    const int tid  = threadIdx.x;
    const int b    = blockIdx.x;
    const int row0 = (b >> 2) * 32;
    const int col  = (b & 3) * 1024 + tid * 4;

    // reduce the 32 K-split partials: 512 (row,rank) values, 2 per thread.
    // per ks pass the 512 addresses are consecutive -> coalesced dword reads.
#pragma unroll
    for (int i = 0; i < 2; ++i) {
        const int idx = i * 256 + tid;          // 0..511 = 32 rows x 16 ranks
        const float* src = hp + (size_t)row0 * RANK + idx;
        float s = 0.0f;
#pragma unroll
        for (int ks = 0; ks < KSPLIT; ++ks)
            s += src[(size_t)ks * 8192 * RANK];
        hs[idx] = 2.0f * s;                     // fold in SCALING
    }

    // B slice into regs: bf[j*16 + rho] = B[col+j][rho]
    float4 breg[16];
    const float4* B4 = (const float4*)(B + (size_t)col * RANK);
#pragma unroll
    for (int i = 0; i < 16; ++i) breg[i] = B4[i];
    const float* bf = (const float*)breg;
    __syncthreads();

    for (int r = 0; r < 32; ++r) {
        const float4 h0 = *(const float4*)(hs + r * RANK);
        const float4 h1 = *(const float4*)(hs + r * RANK + 4);
        const float4 h2 = *(const float4*)(hs + r * RANK + 8);
        const float4 h3 = *(const float4*)(hs + r * RANK + 12);
        const float hv[16] = {h0.x, h0.y, h0.z, h0.w, h1.x, h1.y, h1.z, h1.w,
                              h2.x, h2.y, h2.z, h2.w, h3.x, h3.y, h3.z, h3.w};
        float4 acc = {0.f, 0.f, 0.f, 0.f};
#pragma unroll
        for (int rho = 0; rho < RANK; ++rho) {
            acc.x += hv[rho] * bf[0 * RANK + rho];
            acc.y += hv[rho] * bf[1 * RANK + rho];
            acc.z += hv[rho] * bf[2 * RANK + rho];
            acc.w += hv[rho] * bf[3 * RANK + rho];
        }
        *(float4*)(out + (size_t)(row0 + r) * OUT_F + col) = acc;   // dwordx4
    }
}

extern "C" void kernel_launch(void* const* d_in, const int* in_sizes, int n_in,
                              void* d_out, int out_size, void* d_ws, size_t ws_size,
                              hipStream_t stream) {
    const float* x  = (const float*)d_in[0];   // [4,2048,4096]
    const float* A  = (const float*)d_in[1];   // [16,4096]
    const float* Bm = (const float*)d_in[2];   // [4096,16]
    float* out = (float*)d_out;                // [8192,4096] fp32
    float* At  = (float*)d_ws;                                    // 256 KB
    float* hp  = (float*)((char*)d_ws + (size_t)IN_F * RANK * 4); // 16 MB

    k_transpose<<<256, 256, 0, stream>>>(A, At);
    k_stage1<<<1024, 256, 0, stream>>>(x, At, hp);
    k_stage2<<<1024, 256, 0, stream>>>(hp, Bm, out);
}

// Round 3
// 256.563 us; speedup vs baseline: 1.1468x; 1.1351x over previous
//
#include <hip/hip_runtime.h>

// LoRA forward: out[8192][4096] = (x[8192][4096] @ A^T) @ B^T * 2.0, all fp32.
// Stage1 via bf16 MFMA with hi/lo split-precision (error ~1e-5 << 7.1e-3 thr):
//   h = x@A^T as  xhi*Ahi + xlo*Ahi + xhi*Alo  (fp32 accumulate in MFMA).
// A-operand lives in VGPR B-fragments (loaded ONCE per wave) -- this kills the
// per-k scalar-load chain that pinned rounds 1-2 at ~80 us.
//
// ws layout: hp [32][8192][16] f32 (16 MB) -- 32 k-split partials of h.

#define IN_F  4096
#define OUT_F 4096
#define RANK  16
#define KSPLIT 32
#define KSLICE 128          // 4 ktiles of 32

typedef __attribute__((ext_vector_type(8))) short short8;   // 8 bf16 (4 VGPRs)
typedef __attribute__((ext_vector_type(4))) float f32x4;

static __device__ __forceinline__ short f2bf(float f) {
    union { float f; unsigned u; } v; v.f = f;
    unsigned r = v.u + 0x7fff + ((v.u >> 16) & 1);          // RNE
    return (short)(r >> 16);
}
static __device__ __forceinline__ float bf2f(short h) {
    union { unsigned u; float f; } v; v.u = ((unsigned)(unsigned short)h) << 16;
    return v.f;
}

// ---------------- stage 1: hp[ks][row][rank] = partial x @ A^T (MFMA) ----------
// wave = (64-row group rt=0..3 x 16, 128-k slice). 4096 waves = 1024 blocks.
// frag layouts (16x16x32 bf16): A-frag m=lane&15, k=(lane>>4)*8+j;
// B-frag n=lane&15, k=(lane>>4)*8+j; D col=lane&15, row=(lane>>4)*4+reg.
__global__ __launch_bounds__(256) void k_stage1(const float* __restrict__ x,
                                                const float* __restrict__ A,
                                                float* __restrict__ hp) {
    const int tid  = threadIdx.x;
    const int w    = __builtin_amdgcn_readfirstlane(tid >> 6);
    const int lane = tid & 63;
    const int g    = blockIdx.x * 4 + w;        // 0..4095
    const int rg   = g >> 5;                    // 0..127 -> 64 rows
    const int ks   = g & (KSPLIT - 1);          // 0..31
    const int row0 = rg * 64;
    const int k0   = ks * KSLICE;
    const int n    = lane & 15;                 // rank / frag row
    const int q    = lane >> 4;                 // quad

    // ---- A-matrix as B-fragments, hi/lo, loaded once (32 VGPRs total) ----
    short8 Ahi[4], Alo[4];
#pragma unroll
    for (int kt = 0; kt < 4; ++kt) {
        const float* ap = A + (size_t)n * IN_F + k0 + kt * 32 + q * 8;  // 8 consec floats
        const float4 a0 = *(const float4*)ap;
        const float4 a1 = *(const float4*)(ap + 4);
        const float av[8] = {a0.x, a0.y, a0.z, a0.w, a1.x, a1.y, a1.z, a1.w};
#pragma unroll
        for (int j = 0; j < 8; ++j) {
            const short hi = f2bf(av[j]);
            Ahi[kt][j] = hi;
            Alo[kt][j] = f2bf(av[j] - bf2f(hi));
        }
    }

    f32x4 acc[4];
#pragma unroll
    for (int rt = 0; rt < 4; ++rt) acc[rt] = (f32x4){0.f, 0.f, 0.f, 0.f};

#pragma unroll
    for (int rt = 0; rt < 4; ++rt) {
        const float* xr = x + (size_t)(row0 + rt * 16 + n) * IN_F + k0 + q * 8;
        // issue all 8 x-loads for this row-tile, then cvt+mfma
        float4 v0[4], v1[4];
#pragma unroll
        for (int kt = 0; kt < 4; ++kt) {
            v0[kt] = *(const float4*)(xr + kt * 32);
            v1[kt] = *(const float4*)(xr + kt * 32 + 4);
        }
#pragma unroll
        for (int kt = 0; kt < 4; ++kt) {
            const float xv[8] = {v0[kt].x, v0[kt].y, v0[kt].z, v0[kt].w,
                                 v1[kt].x, v1[kt].y, v1[kt].z, v1[kt].w};
            short8 xhi, xlo;
#pragma unroll
            for (int j = 0; j < 8; ++j) {
                const short hi = f2bf(xv[j]);
                xhi[j] = hi;
                xlo[j] = f2bf(xv[j] - bf2f(hi));
            }
            acc[rt] = __builtin_amdgcn_mfma_f32_16x16x32_bf16(xhi, Ahi[kt], acc[rt], 0, 0, 0);
            acc[rt] = __builtin_amdgcn_mfma_f32_16x16x32_bf16(xlo, Ahi[kt], acc[rt], 0, 0, 0);
            acc[rt] = __builtin_amdgcn_mfma_f32_16x16x32_bf16(xhi, Alo[kt], acc[rt], 0, 0, 0);
        }
    }

    // D layout: col(rank)=n, row=q*4+reg
#pragma unroll
    for (int rt = 0; rt < 4; ++rt) {
#pragma unroll
        for (int r = 0; r < 4; ++r) {
            const int row = row0 + rt * 16 + q * 4 + r;
            hp[((size_t)ks * 8192 + row) * RANK + n] = acc[rt][r];
        }
    }
}

// ---------------- stage 2: out = (sum_ks hp) @ B^T * 2  (fp32 VALU) ----------
// block = 16 rows x 1024 cols; grid = 512 x 4 = 2048 (8 blocks/CU).
__global__ __launch_bounds__(256) void k_stage2(const float* __restrict__ hp,
                                                const float* __restrict__ B,
                                                float* __restrict__ out) {
    __shared__ float hs[16 * RANK];             // 1 KB
    const int tid  = threadIdx.x;
    const int b    = blockIdx.x;
    const int row0 = (b >> 2) * 16;
    const int col  = (b & 3) * 1024 + tid * 4;

    // reduce 32 k-split partials: thread t owns (row,rank)=t; consecutive
    // threads -> consecutive dwords per ks pass (coalesced), 32 independent loads.
    {
        const float* src = hp + (size_t)row0 * RANK + tid;
        float s = 0.0f;
#pragma unroll
        for (int ks = 0; ks < KSPLIT; ++ks)
            s += src[(size_t)ks * 8192 * RANK];
        hs[tid] = 2.0f * s;                     // fold in SCALING
    }

    // B slice into regs: bf[j*16 + rho] = B[col+j][rho]
    float4 breg[16];
    const float4* B4 = (const float4*)(B + (size_t)col * RANK);
#pragma unroll
    for (int i = 0; i < 16; ++i) breg[i] = B4[i];
    const float* bf = (const float*)breg;
    __syncthreads();

    for (int r = 0; r < 16; ++r) {
        const float4 h0 = *(const float4*)(hs + r * RANK);
        const float4 h1 = *(const float4*)(hs + r * RANK + 4);
        const float4 h2 = *(const float4*)(hs + r * RANK + 8);
        const float4 h3 = *(const float4*)(hs + r * RANK + 12);
        const float hv[16] = {h0.x, h0.y, h0.z, h0.w, h1.x, h1.y, h1.z, h1.w,
                              h2.x, h2.y, h2.z, h2.w, h3.x, h3.y, h3.z, h3.w};
        float4 acc = {0.f, 0.f, 0.f, 0.f};
#pragma unroll
        for (int rho = 0; rho < RANK; ++rho) {
            acc.x += hv[rho] * bf[0 * RANK + rho];
            acc.y += hv[rho] * bf[1 * RANK + rho];
            acc.z += hv[rho] * bf[2 * RANK + rho];
            acc.w += hv[rho] * bf[3 * RANK + rho];
        }
        *(float4*)(out + (size_t)(row0 + r) * OUT_F + col) = acc;   // dwordx4
    }
}

extern "C" void kernel_launch(void* const* d_in, const int* in_sizes, int n_in,
                              void* d_out, int out_size, void* d_ws, size_t ws_size,
                              hipStream_t stream) {
    const float* x  = (const float*)d_in[0];   // [4,2048,4096]
    const float* A  = (const float*)d_in[1];   // [16,4096]
    const float* Bm = (const float*)d_in[2];   // [4096,16]
    float* out = (float*)d_out;                // [8192,4096] fp32
    float* hp  = (float*)d_ws;                 // 16 MB

    k_stage1<<<1024, 256, 0, stream>>>(x, A, hp);
    k_stage2<<<2048, 256, 0, stream>>>(hp, Bm, out);
}